// Round 10
// baseline (307.805 us; speedup 1.0000x reference)
//
#include <hip/hip_runtime.h>

typedef _Float16 f16x8 __attribute__((ext_vector_type(8)));
typedef _Float16 f16x4 __attribute__((ext_vector_type(4)));
typedef float f32x4 __attribute__((ext_vector_type(4)));

#define NH 12
#define SEQ 2048
#define DM 768
#define DH 64

// ---------------- cast fp32 -> fp16 (X and the 4 weight matrices) --------
__global__ __launch_bounds__(256) void cast_kernel(
    const float* __restrict__ X, const float* __restrict__ Wq,
    const float* __restrict__ Wk, const float* __restrict__ Wv,
    const float* __restrict__ Wo, _Float16* __restrict__ Xh,
    _Float16* __restrict__ Wall)
{
    size_t base = ((size_t)blockIdx.x * 256 + threadIdx.x) * 8;
    const size_t NX = 3145728, NW = 589824, TOT = NX + 4 * NW;
    if (base >= TOT) return;
    const float* src;
    _Float16* dst;
    if (base < NX) { src = X + base; dst = Xh + base; }
    else {
        size_t r = base - NX;
        int w = (int)(r / NW);
        size_t o = r - (size_t)w * NW;
        src = (w == 0 ? Wq : w == 1 ? Wk : w == 2 ? Wv : Wo) + o;
        dst = Wall + r;
    }
    float4 a = *reinterpret_cast<const float4*>(src);
    float4 b = *reinterpret_cast<const float4*>(src + 4);
    f16x8 h;
    h[0] = (_Float16)a.x; h[1] = (_Float16)a.y; h[2] = (_Float16)a.z; h[3] = (_Float16)a.w;
    h[4] = (_Float16)b.x; h[5] = (_Float16)b.y; h[6] = (_Float16)b.z; h[7] = (_Float16)b.w;
    *reinterpret_cast<f16x8*>(dst) = h;
}

// ---------------- GEMM: out = A[4096x768] @ W^T + bias ------------------
// z=0 -> Q slab, z=1 -> K slab ([b,h,s,d]); z=2 -> V^T ([b,h,d,s]).
// is_out==1: fp32 d_out + bias.
__global__ __launch_bounds__(256) void gemm_kernel(
    const _Float16* __restrict__ A,
    const _Float16* __restrict__ Wbase,
    const float* __restrict__ b0, const float* __restrict__ b1,
    const float* __restrict__ b2,
    _Float16* __restrict__ outQKV, _Float16* __restrict__ outVT,
    float* __restrict__ outF32, int is_out)
{
    __shared__ _Float16 Asm[128 * 64];
    __shared__ _Float16 Bsm[128 * 64];
    const int tid = threadIdx.x;
    const int m0 = blockIdx.x * 128, n0 = blockIdx.y * 128, z = blockIdx.z;
    const _Float16* Wp = Wbase + (size_t)z * 589824;
    const float* bias = (z == 0) ? b0 : (z == 1 ? b1 : b2);
    const int w = tid >> 6, lane = tid & 63, lr = lane & 15, lg = lane >> 4;
    const int wm = w >> 1, wn = w & 1;

    f32x4 acc[4][4] = {};
    for (int kt = 0; kt < 12; ++kt) {
        __syncthreads();
        #pragma unroll
        for (int i = 0; i < 4; ++i) {
            int c = tid + i * 256;
            int row = c >> 3, col = (c & 7) * 8;
            int sw = (row & 7) << 4;
            f16x8 av = *reinterpret_cast<const f16x8*>(A + (size_t)(m0 + row) * 768 + kt * 64 + col);
            *reinterpret_cast<f16x8*>((char*)Asm + ((row * 128 + col * 2) ^ sw)) = av;
            f16x8 bv = *reinterpret_cast<const f16x8*>(Wp + (size_t)(n0 + row) * 768 + kt * 64 + col);
            *reinterpret_cast<f16x8*>((char*)Bsm + ((row * 128 + col * 2) ^ sw)) = bv;
        }
        __syncthreads();
        #pragma unroll
        for (int kf = 0; kf < 2; ++kf) {
            f16x8 af[4], bf[4];
            #pragma unroll
            for (int mi = 0; mi < 4; ++mi) {
                int row = wm * 64 + mi * 16 + lr;
                af[mi] = *reinterpret_cast<const f16x8*>(
                    (char*)Asm + ((row * 128 + kf * 64 + lg * 16) ^ ((row & 7) << 4)));
            }
            #pragma unroll
            for (int nj = 0; nj < 4; ++nj) {
                int row = wn * 64 + nj * 16 + lr;
                bf[nj] = *reinterpret_cast<const f16x8*>(
                    (char*)Bsm + ((row * 128 + kf * 64 + lg * 16) ^ ((row & 7) << 4)));
            }
            #pragma unroll
            for (int mi = 0; mi < 4; ++mi)
                #pragma unroll
                for (int nj = 0; nj < 4; ++nj)
                    acc[mi][nj] = __builtin_amdgcn_mfma_f32_16x16x32_f16(
                        af[mi], bf[nj], acc[mi][nj], 0, 0, 0);
        }
    }
    #pragma unroll
    for (int mi = 0; mi < 4; ++mi) {
        #pragma unroll
        for (int nj = 0; nj < 4; ++nj) {
            #pragma unroll
            for (int r = 0; r < 4; ++r) {
                int gm = m0 + wm * 64 + mi * 16 + lg * 4 + r;
                int gn = n0 + wn * 64 + nj * 16 + lr;
                float v = acc[mi][nj][r] + bias[gn];
                if (!is_out) {
                    int bb = gm >> 11, s = gm & 2047, hh = gn >> 6, dd = gn & 63;
                    if (z == 2)
                        outVT[(((size_t)bb * NH + hh) * DH + dd) * SEQ + s] = (_Float16)v;
                    else
                        outQKV[(size_t)z * 3145728 +
                               ((((size_t)bb * NH + hh) * SEQ + s) * DH + dd)] = (_Float16)v;
                } else {
                    outF32[(size_t)gm * 768 + gn] = v;
                }
            }
        }
    }
}

// ---------------- flash attention: barrier-free, deep pb pipeline --------
// Block = (h, 32 q-rows) x BOTH batches. 4 waves: w>>1 = batch, w&1 = 16-row
// half. NO __syncthreads in the loop (no vmcnt(0) drains): K and V^T frags
// are loaded direct from global (L2-hot, 32 sibling blocks share tiles); LDS
// holds only the wave-private P tile. pb prefetch = depth-2 register slots
// holding RAW loads (no arithmetic at issue site -> no same-iteration wait);
// (pb+mask)*log2e applied at consume time, 2 iterations after issue.
__global__ __launch_bounds__(256) void attn_kernel(
    const _Float16* __restrict__ Qh, const _Float16* __restrict__ Kh,
    const _Float16* __restrict__ VTg, const float* __restrict__ pb,
    const float* __restrict__ mask, _Float16* __restrict__ ctx)
{
    __shared__ _Float16 Pl[4 * 16 * 64];  // per-wave P tile, 8KB total
    const int tid = threadIdx.x, w = tid >> 6, lane = tid & 63;
    const int lr = lane & 15, lg = lane >> 4;
    const int bsel = w >> 1, wl = w & 1;
    // XCD-aware decode: 768 blocks = 8 XCD * 96; g -> (h, q0)
    const int lin = blockIdx.x;
    const int g = (lin & 7) * 96 + (lin >> 3);
    const int h = g >> 6;
    const int q0 = (g & 63) << 5;          // 32 q-rows per block
    const size_t headoff = ((size_t)bsel * NH + h) * SEQ * DH;
    const _Float16* Qp = Qh + headoff;
    const _Float16* Kp = Kh + headoff;
    const _Float16* VTp = VTg + headoff;   // [d][s] per head
    const float L2E = 1.44269504f;
    const float SC = 0.18033688f;          // 0.125 * log2e

    // Q B-frags (q = lr within the wave's 16 rows)
    f16x8 qfr[2];
    #pragma unroll
    for (int kf = 0; kf < 2; ++kf)
        qfr[kf] = *reinterpret_cast<const f16x8*>(
            Qp + (size_t)(q0 + wl * 16 + lr) * DH + kf * 32 + lg * 8);

    // pb row pointer: no batch term — wave-pairs (0,2) and (1,3) share
    const float* pbq = pb + (size_t)h * SEQ * SEQ + (size_t)(q0 + wl * 16 + lr) * SEQ;
    const float* mrow = mask + (size_t)bsel * SEQ;

    f32x4 oacc[4] = {};
    float m_r = -3.0e38f, l_r = 0.f;
    char* Pw = (char*)Pl + w * 2048;

    // prologue: RAW pb tiles 0 and 1 into the two slots (no math attached)
    f32x4 pbA[4], pbB[4];
    #pragma unroll
    for (int cf = 0; cf < 4; ++cf)
        pbA[cf] = *reinterpret_cast<const f32x4*>(pbq + cf * 16 + lg * 4);
    #pragma unroll
    for (int cf = 0; cf < 4; ++cf)
        pbB[cf] = *reinterpret_cast<const f32x4*>(pbq + 64 + cf * 16 + lg * 4);

    auto body = [&](int it, f32x4 (&slot)[4]) {
        const int ktg = it * 64;
        const int pt = ((it + 2 < 32) ? it + 2 : 31) * 64;

        // ---- QK^T swapped: S[kt][q], K frags direct from global ----
        f32x4 sc4[4] = {};
        #pragma unroll
        for (int cf = 0; cf < 4; ++cf) {
            f16x8 ka0 = *reinterpret_cast<const f16x8*>(
                Kp + (size_t)(ktg + cf * 16 + lr) * DH + lg * 8);
            f16x8 ka1 = *reinterpret_cast<const f16x8*>(
                Kp + (size_t)(ktg + cf * 16 + lr) * DH + 32 + lg * 8);
            sc4[cf] = __builtin_amdgcn_mfma_f32_16x16x32_f16(ka0, qfr[0], sc4[cf], 0, 0, 0);
            sc4[cf] = __builtin_amdgcn_mfma_f32_16x16x32_f16(ka1, qfr[1], sc4[cf], 0, 0, 0);
        }

        // ---- consume pb slot (loaded 2 iterations ago); mask is L1-hot ----
        #pragma unroll
        for (int cf = 0; cf < 4; ++cf) {
            f32x4 mk = *reinterpret_cast<const f32x4*>(mrow + ktg + cf * 16 + lg * 4);
            sc4[cf] = sc4[cf] * SC + (slot[cf] + mk) * L2E;
        }
        // ---- refill slot: RAW loads only, consumed 2 iterations later ----
        #pragma unroll
        for (int cf = 0; cf < 4; ++cf)
            slot[cf] = *reinterpret_cast<const f32x4*>(pbq + pt + cf * 16 + lg * 4);

        // ---- online softmax: q-row lr lane-local, xor 16/32 ----
        float t = sc4[0][0];
        #pragma unroll
        for (int cf = 0; cf < 4; ++cf)
            #pragma unroll
            for (int r = 0; r < 4; ++r) t = fmaxf(t, sc4[cf][r]);
        t = fmaxf(t, __shfl_xor(t, 16));
        t = fmaxf(t, __shfl_xor(t, 32));
        float mn = fmaxf(m_r, t);
        float sscale = exp2f(m_r - mn);
        m_r = mn;
        float rs = 0.f;
        #pragma unroll
        for (int cf = 0; cf < 4; ++cf) {
            f16x4 pv;
            #pragma unroll
            for (int r = 0; r < 4; ++r) {
                float p = exp2f(sc4[cf][r] - mn);
                rs += p;
                pv[r] = (_Float16)p;
            }
            *reinterpret_cast<f16x4*>(
                Pw + ((lr * 128 + cf * 32 + lg * 8) ^ ((lr & 7) << 4))) = pv;
        }
        rs += __shfl_xor(rs, 16);
        rs += __shfl_xor(rs, 32);
        l_r = l_r * sscale + rs;
        f32x4 scv = {__shfl(sscale, lg * 4 + 0), __shfl(sscale, lg * 4 + 1),
                     __shfl(sscale, lg * 4 + 2), __shfl(sscale, lg * 4 + 3)};
        #pragma unroll
        for (int cf = 0; cf < 4; ++cf) oacc[cf] *= scv;

        // ---- PV: A = P (wave-private LDS round-trip), B = V^T direct ----
        #pragma unroll
        for (int kf = 0; kf < 2; ++kf) {
            f16x8 pa = *reinterpret_cast<const f16x8*>(
                Pw + ((lr * 128 + kf * 64 + lg * 16) ^ ((lr & 7) << 4)));
            #pragma unroll
            for (int cf = 0; cf < 4; ++cf) {
                f16x8 vb = *reinterpret_cast<const f16x8*>(
                    VTp + (size_t)(cf * 16 + lr) * SEQ + ktg + kf * 32 + lg * 8);
                oacc[cf] = __builtin_amdgcn_mfma_f32_16x16x32_f16(pa, vb, oacc[cf], 0, 0, 0);
            }
        }
    };

    for (int mi = 0; mi < 16; ++mi) {
        body(mi * 2, pbA);
        body(mi * 2 + 1, pbB);
    }

    // epilogue: normalize and write ctx[bsel, s, h*64+d] fp16
    float linv = 1.0f / l_r;
    f32x4 iv = {__shfl(linv, lg * 4 + 0), __shfl(linv, lg * 4 + 1),
                __shfl(linv, lg * 4 + 2), __shfl(linv, lg * 4 + 3)};
    #pragma unroll
    for (int r = 0; r < 4; ++r) {
        int grow = q0 + wl * 16 + lg * 4 + r;
        #pragma unroll
        for (int cf = 0; cf < 4; ++cf)
            ctx[((size_t)bsel * SEQ + grow) * DM + h * DH + cf * 16 + lr] =
                (_Float16)(oacc[cf][r] * iv[r]);
    }
}

extern "C" void kernel_launch(void* const* d_in, const int* in_sizes, int n_in,
                              void* d_out, int out_size, void* d_ws, size_t ws_size,
                              hipStream_t stream) {
    const float* X    = (const float*)d_in[0];
    const float* mask = (const float*)d_in[1];
    const float* pb   = (const float*)d_in[2];
    const float* Wq   = (const float*)d_in[3];
    const float* bq   = (const float*)d_in[4];
    const float* Wk   = (const float*)d_in[5];
    const float* bk   = (const float*)d_in[6];
    const float* Wv   = (const float*)d_in[7];
    const float* bv   = (const float*)d_in[8];
    const float* Wo   = (const float*)d_in[9];
    const float* bo   = (const float*)d_in[10];
    float* out = (float*)d_out;

    _Float16* Xh   = (_Float16*)d_ws;              // 3145728 f16
    _Float16* Wall = Xh + 3145728;                 // 4 * 589824 f16
    _Float16* QK   = Wall + 4 * 589824;            // Q,K slabs: 2 * 3145728
    _Float16* VT   = QK + 2 * 3145728;             // V^T: 3145728
    _Float16* ctx  = VT + 3145728;                 // 3145728

    cast_kernel<<<2688, 256, 0, stream>>>(X, Wq, Wk, Wv, Wo, Xh, Wall);
    gemm_kernel<<<dim3(32, 6, 3), 256, 0, stream>>>(
        Xh, Wall, bq, bk, bv, QK, VT, nullptr, 0);
    attn_kernel<<<768, 256, 0, stream>>>(
        QK, QK + 3145728, VT, pb, mask, ctx);
    gemm_kernel<<<dim3(32, 6, 1), 256, 0, stream>>>(
        ctx, Wall + 3 * 589824, bo, bo, bo, nullptr, nullptr, out, 1);
}